// Round 6
// baseline (159.746 us; speedup 1.0000x reference)
//
#include <hip/hip_runtime.h>

#define B_ 16
#define T_ 12
#define N_ 512
#define D_ 128
#define E_ 32

typedef __attribute__((ext_vector_type(8))) unsigned short u16x8;
typedef __attribute__((ext_vector_type(8))) __bf16 bf16x8;
typedef __attribute__((ext_vector_type(4))) float f32x4;

static __device__ __forceinline__ unsigned short f2bf(float f) {
    unsigned u = __float_as_uint(f);
    unsigned r = (u + 0x7fffu + ((u >> 16) & 1u)) >> 16;
    return (unsigned short)r;
}

static __device__ __forceinline__ void gld16(const void* src, void* dst) {
    __builtin_amdgcn_global_load_lds(
        (const __attribute__((address_space(1))) unsigned*)src,
        (__attribute__((address_space(3))) unsigned*)dst, 16, 0, 0);
}

// ---------------------------------------------------------------------------
// k1: ALL input-only stages in one wide launch (XCD-swizzled block ids):
//  [0,192):     kN: qk recomputed from emb (gld16-staged swizzled LDS),
//               softmax over n -> kN bf16.
//  [192,576):   qProj: qk row + softmax over D -> qb bf16 (wave-autonomous).
//  [576,1088):  mask -> packed bitwords
//  [1088,1152): WvT[d][k] = bf16(Wv[k][d])
// ---------------------------------------------------------------------------
__global__ __launch_bounds__(256) void k1(const float* __restrict__ emb,
                                          const float* __restrict__ Wqk,
                                          const float* __restrict__ bqk,
                                          unsigned short* __restrict__ qb,
                                          unsigned short* __restrict__ kN,
                                          const float* __restrict__ Wv,
                                          unsigned short* __restrict__ WvT,
                                          const int* __restrict__ mask,
                                          unsigned* __restrict__ mb) {
    __shared__ __align__(16) char LE[256 * 128];  // 32 KB: 256 emb rows swizzled
    __shared__ float red[2][4][8];
    int hwid = blockIdx.x;
    int bid = (hwid & 7) * 144 + (hwid >> 3);  // XCD swizzle (1152 = 8*144)
    int tid = threadIdx.x;

    if (bid < 192) {  // ---- kN: softmax over n ----
        int t = bid >> 4;
        int d0 = (bid & 15) * 8;
        int dc = tid & 7, ni = tid >> 3;  // ni 0..31
        int wave = tid >> 6, lane = tid & 63;
        int l3 = lane >> 3, l7 = lane & 7;
        float wqv[E_];
#pragma unroll
        for (int e = 0; e < E_; ++e) wqv[e] = Wqk[e * D_ + d0 + dc];
        float bq = bqk[d0 + dc];
        const char* eb = (const char*)(emb + (size_t)t * N_ * E_);

        float vals[16];
#pragma unroll
        for (int pass = 0; pass < 2; ++pass) {
#pragma unroll
            for (int it = 0; it < 8; ++it) {
                int rl = it * 32 + wave * 8 + l3;          // local row 0..255
                int rg = pass * 256 + rl;                  // global row
                gld16(eb + (size_t)rg * 128 + ((l7 * 16) ^ ((rg & 7) << 4)),
                      LE + (it * 32 + wave * 8) * 128 + lane * 16);
            }
            __syncthreads();
#pragma unroll
            for (int jj = 0; jj < 8; ++jj) {
                int n = pass * 256 + ni + 32 * jj;
                int nl = ni + 32 * jj;
                float a = bq;
#pragma unroll
                for (int s = 0; s < 8; ++s) {
                    f32x4 ev = *(const f32x4*)(LE + nl * 128 +
                                               ((s * 16) ^ ((n & 7) << 4)));
                    a = fmaf(ev[0], wqv[s * 4 + 0], a);
                    a = fmaf(ev[1], wqv[s * 4 + 1], a);
                    a = fmaf(ev[2], wqv[s * 4 + 2], a);
                    a = fmaf(ev[3], wqv[s * 4 + 3], a);
                }
                vals[pass * 8 + jj] = a;
            }
            __syncthreads();
        }

        float mx = -1e30f;
#pragma unroll
        for (int j = 0; j < 16; ++j) mx = fmaxf(mx, vals[j]);
#pragma unroll
        for (int s = 8; s < 64; s <<= 1) mx = fmaxf(mx, __shfl_xor(mx, s));
        int wv = tid >> 6;
        if ((tid & 63) < 8) red[0][wv][dc] = mx;
        __syncthreads();
        mx = fmaxf(fmaxf(red[0][0][dc], red[0][1][dc]),
                   fmaxf(red[0][2][dc], red[0][3][dc]));
        float sum = 0.f;
#pragma unroll
        for (int j = 0; j < 16; ++j) {
            vals[j] = __expf(vals[j] - mx);
            sum += vals[j];
        }
#pragma unroll
        for (int s = 8; s < 64; s <<= 1) sum += __shfl_xor(sum, s);
        if ((tid & 63) < 8) red[1][wv][dc] = sum;
        __syncthreads();
        sum = red[1][0][dc] + red[1][1][dc] + red[1][2][dc] + red[1][3][dc];
        float inv = 1.f / sum;
        unsigned short* op = kN + (size_t)t * N_ * D_ + d0 + dc;
#pragma unroll
        for (int j = 0; j < 16; ++j)
            op[(size_t)(ni + 32 * j) * D_] = f2bf(vals[j] * inv);
        return;
    }

    if (bid < 576) {  // ---- qProj + softmax over D ----
        int bid2 = bid - 192;
        int w = tid >> 6, l = tid & 63;
        float wq0[E_], wq1[E_];
#pragma unroll
        for (int e = 0; e < E_; ++e) {
            wq0[e] = Wqk[e * D_ + l];
            wq1[e] = Wqk[e * D_ + l + 64];
        }
        float b0 = bqk[l], b1 = bqk[l + 64];
        for (int rr = 0; rr < 4; ++rr) {
            int tn = bid2 * 16 + w * 4 + rr;  // wave-uniform
            const float* ep = emb + (size_t)tn * E_;
            float a0 = b0, a1 = b1;
#pragma unroll
            for (int e = 0; e < E_; ++e) {
                float ev = ep[e];
                a0 = fmaf(ev, wq0[e], a0);
                a1 = fmaf(ev, wq1[e], a1);
            }
            float mx = fmaxf(a0, a1);
#pragma unroll
            for (int s = 32; s > 0; s >>= 1) mx = fmaxf(mx, __shfl_xor(mx, s));
            float e0 = __expf(a0 - mx), e1 = __expf(a1 - mx);
            float sum = e0 + e1;
#pragma unroll
            for (int s = 32; s > 0; s >>= 1) sum += __shfl_xor(sum, s);
            float inv = 1.f / sum;
            qb[(size_t)tn * D_ + l] = f2bf(e0 * inv);
            qb[(size_t)tn * D_ + l + 64] = f2bf(e1 * inv);
        }
        return;
    }

    if (bid < 1088) {  // ---- mask pack ----
        int o = (bid - 576) * 256 + tid;  // 0..131071
        const int* mp = mask + (size_t)o * 32;
        unsigned bits = 0;
#pragma unroll
        for (int j = 0; j < 32; j += 4) {
            int4 m4 = *(const int4*)&mp[j];
            bits |= (m4.x ? 1u : 0u) << j;
            bits |= (m4.y ? 1u : 0u) << (j + 1);
            bits |= (m4.z ? 1u : 0u) << (j + 2);
            bits |= (m4.w ? 1u : 0u) << (j + 3);
        }
        mb[o] = bits;
        return;
    }

    {  // ---- WvT ----
        int i = (bid - 1088) * 256 + tid;  // 0..16383
        int d = i >> 7, k = i & 127;
        WvT[d * 128 + k] = f2bf(Wv[k * 128 + d]);
    }
}

// ---------------------------------------------------------------------------
// kF: 2-chunk K-split pipeline (anchor, r4/r5 structure), XCD-swizzled ids.
//  [0,192):   A3m: sc = qb @ kN^T
//  [192,960): Bm:  vT[bt][d][m] = WvT @ value^T + bv (value fp32 reg-staged)
// ---------------------------------------------------------------------------
__global__ __launch_bounds__(256, 2) void kF(const unsigned short* __restrict__ qb,
                                             const unsigned short* __restrict__ kN,
                                             unsigned short* __restrict__ sc,
                                             const float* __restrict__ value,
                                             const unsigned short* __restrict__ WvT,
                                             const float* __restrict__ bv,
                                             unsigned short* __restrict__ vT) {
    __shared__ __align__(16) char LA[2][128 * 128];  // 32 KB (A tile, 2 chunks)
    __shared__ __align__(16) char LB[2][128 * 128];  // 32 KB (B tile, 2 chunks)
    int hwid = blockIdx.x;
    int bid = (hwid & 7) * 120 + (hwid >> 3);  // XCD swizzle (960 = 8*120)
    int tid = threadIdx.x;
    int wave = tid >> 6, lane = tid & 63;
    int q = lane >> 4, lr = lane & 15;
    int rbase = (wave & 1) * 64, cbase = (wave >> 1) * 64;
    int l3 = lane >> 3, l7 = lane & 7;

    f32x4 acc[4][4];
#pragma unroll
    for (int i = 0; i < 4; ++i)
#pragma unroll
        for (int j = 0; j < 4; ++j) acc[i][j] = (f32x4){0.f, 0.f, 0.f, 0.f};

#define STAGE_T(gbase, lb, c)                                                   \
    _Pragma("unroll") for (int it_ = 0; it_ < 4; ++it_) {                       \
        int row_ = it_ * 32 + wave * 8 + l3;                                    \
        gld16((gbase) + (size_t)row_ * 256 + (c) * 128 +                        \
                  ((l7 * 16) ^ ((row_ & 7) << 4)),                              \
              (lb) + (it_ * 32 + wave * 8) * 128 + lane * 16);                  \
    }

#define MFMA_CHUNK(c)                                                           \
    _Pragma("unroll") for (int ksl_ = 0; ksl_ < 2; ++ksl_) {                    \
        bf16x8 a_[4], b_[4];                                                    \
        _Pragma("unroll") for (int i_ = 0; i_ < 4; ++i_) {                      \
            int r_ = rbase + 16 * i_ + lr;                                      \
            a_[i_] = *(const bf16x8*)(LA[c] + r_ * 128 +                        \
                                      ((ksl_ * 64 + q * 16) ^ ((r_ & 7) << 4)));\
        }                                                                       \
        _Pragma("unroll") for (int j_ = 0; j_ < 4; ++j_) {                      \
            int r_ = cbase + 16 * j_ + lr;                                      \
            b_[j_] = *(const bf16x8*)(LB[c] + r_ * 128 +                        \
                                      ((ksl_ * 64 + q * 16) ^ ((r_ & 7) << 4)));\
        }                                                                       \
        _Pragma("unroll") for (int i_ = 0; i_ < 4; ++i_)                        \
            _Pragma("unroll") for (int j_ = 0; j_ < 4; ++j_)                    \
                acc[i_][j_] = __builtin_amdgcn_mfma_f32_16x16x32_bf16(          \
                    a_[i_], b_[j_], acc[i_][j_], 0, 0, 0);                      \
    }

    if (bid < 192) {  // ---- A3m ----
        int mt = bid & 3, nt = (bid >> 2) & 3, t = bid >> 4;
        int n0 = nt * 128, m0 = mt * 128;
        const char* qp = (const char*)(qb + (size_t)t * N_ * D_ + (size_t)n0 * D_);
        const char* kp = (const char*)(kN + (size_t)t * N_ * D_ + (size_t)m0 * D_);
        STAGE_T(qp, LA[0], 0)
        STAGE_T(kp, LB[0], 0)
        STAGE_T(qp, LA[1], 1)
        STAGE_T(kp, LB[1], 1)
        asm volatile("s_waitcnt vmcnt(8)" ::: "memory");
        __builtin_amdgcn_sched_barrier(0);
        __builtin_amdgcn_s_barrier();
        __builtin_amdgcn_sched_barrier(0);
        MFMA_CHUNK(0)
        asm volatile("s_waitcnt vmcnt(0)" ::: "memory");
        __builtin_amdgcn_sched_barrier(0);
        __builtin_amdgcn_s_barrier();
        __builtin_amdgcn_sched_barrier(0);
        MFMA_CHUNK(1)

        unsigned short* sp = sc + (size_t)t * N_ * N_;
#pragma unroll
        for (int i = 0; i < 4; ++i)
#pragma unroll
            for (int j = 0; j < 4; ++j) {
                int row0 = n0 + rbase + 16 * i + q * 4;
                int col = m0 + cbase + 16 * j + lr;
#pragma unroll
                for (int e = 0; e < 4; ++e)
                    sp[(size_t)(row0 + e) * N_ + col] = f2bf(acc[i][j][e]);
            }
        return;
    }

    // ---- Bm ----
    {
        int idx = bid - 192;
        int mt = idx & 3, bt = idx >> 2;
        int m0 = mt * 128;
        const float* vp = value + ((size_t)bt * N_ + m0) * D_;
        const char* wp = (const char*)WvT;
        int g = tid >> 4, c16 = tid & 15;

        float4 v0[8], v1[8];
#pragma unroll
        for (int jj = 0; jj < 8; ++jj)
            v0[jj] = *(const float4*)(vp + (size_t)(g * 8 + jj) * D_ + c16 * 4);
        __builtin_amdgcn_sched_barrier(0);
        STAGE_T(wp, LA[0], 0)
        __builtin_amdgcn_sched_barrier(0);
#pragma unroll
        for (int jj = 0; jj < 8; ++jj)
            v1[jj] = *(const float4*)(vp + (size_t)(g * 8 + jj) * D_ + 64 + c16 * 4);
        __builtin_amdgcn_sched_barrier(0);
        STAGE_T(wp, LA[1], 1)
        __builtin_amdgcn_sched_barrier(0);

#pragma unroll
        for (int jj = 0; jj < 8; ++jj) {
            int row = g * 8 + jj;
            ushort4 o;
            o.x = f2bf(v0[jj].x); o.y = f2bf(v0[jj].y);
            o.z = f2bf(v0[jj].z); o.w = f2bf(v0[jj].w);
            *(ushort4*)(LB[0] + row * 128 + ((c16 * 8) ^ ((row & 7) << 4))) = o;
        }
        asm volatile("s_waitcnt vmcnt(12) lgkmcnt(0)" ::: "memory");
        __builtin_amdgcn_sched_barrier(0);
        __builtin_amdgcn_s_barrier();
        __builtin_amdgcn_sched_barrier(0);
        MFMA_CHUNK(0)
#pragma unroll
        for (int jj = 0; jj < 8; ++jj) {
            int row = g * 8 + jj;
            ushort4 o;
            o.x = f2bf(v1[jj].x); o.y = f2bf(v1[jj].y);
            o.z = f2bf(v1[jj].z); o.w = f2bf(v1[jj].w);
            *(ushort4*)(LB[1] + row * 128 + ((c16 * 8) ^ ((row & 7) << 4))) = o;
        }
        asm volatile("s_waitcnt vmcnt(0) lgkmcnt(0)" ::: "memory");
        __builtin_amdgcn_sched_barrier(0);
        __builtin_amdgcn_s_barrier();
        __builtin_amdgcn_sched_barrier(0);
        MFMA_CHUNK(1)

        unsigned short* op = vT + (size_t)bt * N_ * D_;
#pragma unroll
        for (int i = 0; i < 4; ++i) {
            int row0 = rbase + 16 * i + q * 4;
            float4 bq = *(const float4*)&bv[row0];
#pragma unroll
            for (int j = 0; j < 4; ++j) {
                int col = m0 + cbase + 16 * j + lr;
                op[(size_t)(row0 + 0) * N_ + col] = f2bf(acc[i][j][0] + bq.x);
                op[(size_t)(row0 + 1) * N_ + col] = f2bf(acc[i][j][1] + bq.y);
                op[(size_t)(row0 + 2) * N_ + col] = f2bf(acc[i][j][2] + bq.z);
                op[(size_t)(row0 + 3) * N_ + col] = f2bf(acc[i][j][3] + bq.w);
            }
        }
    }
#undef STAGE_T
#undef MFMA_CHUNK
}

// ---------------------------------------------------------------------------
// kC: out[b,t,n,d] = sum_m (mask ? score0 : -1e9) * v[b,t,m,d] via bf16 MFMA.
// NEW: single-barrier-per-chunk pipeline. Sb AND Vb double-buffered (64 KB,
// 2 blocks/CU). Per chunk kc: issue V(kc+1) gld16 + sreg(kc+2) loads, one
// counted s_waitcnt vmcnt(9) (drains V(kc)+sreg(kc+1), keeps 9 newest in
// flight — never 0 mid-loop), MFMA(kc), then merge(kc+1) in the MFMA shadow,
// lgkmcnt(0), s_barrier. 8 barriers total (was 16), no full drains.
// ---------------------------------------------------------------------------
__global__ __launch_bounds__(256, 2) void kC(const unsigned short* __restrict__ sc,
                                             const unsigned* __restrict__ mb,
                                             const unsigned short* __restrict__ vT,
                                             float* __restrict__ out) {
    int hwid = blockIdx.x;
    int w = (hwid & 7) * 96 + (hwid >> 3);  // XCD swizzle (768 = 8*96)
    int n0 = (w & 3) * 128;
    int r = w >> 2;
    int t = r % T_, b = r / T_;
    int tid = threadIdx.x;
    int wave = tid >> 6, lane = tid & 63;
    int q = lane >> 4, lr = lane & 15;
    int rbase = (wave & 1) * 64, cbase = (wave >> 1) * 64;

    __shared__ __align__(16) unsigned short Sb[2][128 * 64];  // 2 x 16 KB
    __shared__ __align__(16) unsigned short Vb[2][128 * 64];  // 2 x 16 KB

    const unsigned short* scp = sc + (size_t)t * N_ * N_ + (size_t)n0 * N_;
    const unsigned short* vtp = vT + ((size_t)(b * T_ + t)) * N_ * D_;  // [d][m]
    const unsigned* mbp = mb + ((size_t)b * N_ + n0) * 16;
    const unsigned short NEG = 0xCE6E;  // bf16(-1e9)

    f32x4 acc[4][4];
#pragma unroll
    for (int i = 0; i < 4; ++i)
#pragma unroll
        for (int j = 0; j < 4; ++j) acc[i][j] = (f32x4){0.f, 0.f, 0.f, 0.f};

    int sr = tid >> 1, sh2 = tid & 1;
    const unsigned short* sg = scp + (size_t)sr * N_ + sh2 * 32;
    const unsigned* mwp = mbp + sr * 16 + sh2;
    int swz_r = (sr & 7) << 4;

    int l3 = lane >> 3, l7 = lane & 7;
    int vin = (l7 * 16) ^ (l3 << 4);
    const char* vbase = (const char*)vtp;

    u16x8 sreg[2][4];
    unsigned mwv[2];

// issue 4 gld16 of V chunk kc into Vb[buf]
#define VISS(buf, kc)                                                           \
    _Pragma("unroll") for (int it_ = 0; it_ < 4; ++it_) {                       \
        int row_ = (it_ * 4 + wave) * 8 + l3;                                   \
        gld16(vbase + (size_t)row_ * 1024 + (kc) * 128 + vin,                   \
              (char*)Vb[buf] + ((it_ * 4 + wave) * 64 + lane) * 16);            \
    }

// load raw S chunk kc + mask word into register set s
#define SLOAD(s, kc)                                                            \
    _Pragma("unroll") for (int p_ = 0; p_ < 4; ++p_)                            \
        sreg[s][p_] = *(const u16x8*)(sg + (kc) * 64 + p_ * 8);                 \
    mwv[s] = mwp[(kc) * 2];

// masked merge of register set s into Sb[buf] (swizzled ds_writes)
#define MERGE(buf, s)                                                           \
    _Pragma("unroll") for (int p_ = 0; p_ < 4; ++p_) {                          \
        unsigned bits_ = mwv[s] >> (p_ * 8);                                    \
        u16x8 o_;                                                               \
        _Pragma("unroll") for (int j_ = 0; j_ < 8; ++j_)                        \
            o_[j_] = ((bits_ >> j_) & 1u) ? sreg[s][p_][j_] : NEG;              \
        *(u16x8*)((char*)Sb[buf] + sr * 128 + ((sh2 * 64 + p_ * 16) ^ swz_r)) = \
            o_;                                                                 \
    }

// 32 MFMAs on chunk buffers Sb[c], Vb[c]
#define MFMAC(c)                                                                \
    {                                                                           \
        const char* Sbase_ = (const char*)Sb[c];                                \
        const char* Vbase_ = (const char*)Vb[c];                                \
        int swz_l_ = (lr & 7) << 4;                                             \
        _Pragma("unroll") for (int ks_ = 0; ks_ < 2; ++ks_) {                   \
            bf16x8 a_[4], bb_[4];                                               \
            _Pragma("unroll") for (int i_ = 0; i_ < 4; ++i_) {                  \
                int r_ = rbase + 16 * i_ + lr;                                  \
                a_[i_] = *(const bf16x8*)(Sbase_ + r_ * 128 +                   \
                                          ((ks_ * 64 + q * 16) ^ swz_l_));      \
            }                                                                   \
            _Pragma("unroll") for (int j_ = 0; j_ < 4; ++j_) {                  \
                int d_ = cbase + 16 * j_ + lr;                                  \
                bb_[j_] = *(const bf16x8*)(Vbase_ + d_ * 128 +                  \
                                           ((ks_ * 64 + q * 16) ^ swz_l_));     \
            }                                                                   \
            _Pragma("unroll") for (int i_ = 0; i_ < 4; ++i_)                    \
                _Pragma("unroll") for (int j_ = 0; j_ < 4; ++j_)                \
                    acc[i_][j_] = __builtin_amdgcn_mfma_f32_16x16x32_bf16(      \
                        a_[i_], bb_[j_], acc[i_][j_], 0, 0, 0);                 \
        }                                                                       \
    }

    // ---- prologue: V(0) in flight, chunk0 merged to Sb[0], chunk1 in regs ----
    VISS(0, 0)
    SLOAD(0, 0)
    SLOAD(1, 1)
    asm volatile("s_waitcnt vmcnt(5)" ::: "memory");  // V(0)+sreg0 done; sreg1 flies
    __builtin_amdgcn_sched_barrier(0);
    MERGE(0, 0)
    asm volatile("s_waitcnt lgkmcnt(0)" ::: "memory");
    __builtin_amdgcn_s_barrier();
    __builtin_amdgcn_sched_barrier(0);

#pragma unroll
    for (int kc = 0; kc < 8; ++kc) {
        int cur = kc & 1, nxt = cur ^ 1;
        if (kc < 7) { VISS(nxt, kc + 1) }          // 4 vm ops
        if (kc < 6) { SLOAD(cur, kc + 2) }         // 5 vm ops
        // counted drain: V(kc) [+ merge operands] complete; newest stay in flight
        if (kc < 6) {
            asm volatile("s_waitcnt vmcnt(9)" ::: "memory");
        } else if (kc == 6) {
            asm volatile("s_waitcnt vmcnt(4)" ::: "memory");
        } else {
            asm volatile("s_waitcnt vmcnt(0)" ::: "memory");
        }
        __builtin_amdgcn_sched_barrier(0);
        MFMAC(cur)
        if (kc < 7) { MERGE(nxt, nxt) }            // fills the MFMA shadow
        asm volatile("s_waitcnt lgkmcnt(0)" ::: "memory");
        if (kc < 7) {
            __builtin_amdgcn_s_barrier();
            __builtin_amdgcn_sched_barrier(0);
        }
    }

#undef VISS
#undef SLOAD
#undef MERGE
#undef MFMAC

    float* ob = out + ((size_t)(b * T_ + t)) * N_ * D_;
#pragma unroll
    for (int i = 0; i < 4; ++i) {
#pragma unroll
        for (int j = 0; j < 4; ++j) {
            int row0 = n0 + rbase + 16 * i + q * 4;
            int col = cbase + 16 * j + lr;
#pragma unroll
            for (int e = 0; e < 4; ++e)
                ob[(size_t)(row0 + e) * D_ + col] = acc[i][j][e];
        }
    }
}

// ---------------------------------------------------------------------------
extern "C" void kernel_launch(void* const* d_in, const int* in_sizes, int n_in,
                              void* d_out, int out_size, void* d_ws, size_t ws_size,
                              hipStream_t stream) {
    const float* value = (const float*)d_in[0];
    const float* emb   = (const float*)d_in[1];
    const int*   mask  = (const int*)d_in[2];
    const float* Wqk   = (const float*)d_in[3];
    const float* bqk   = (const float*)d_in[4];
    const float* Wv    = (const float*)d_in[5];
    const float* bvv   = (const float*)d_in[6];
    float* out = (float*)d_out;

    float* ws = (float*)d_ws;
    unsigned short* qb   = (unsigned short*)(ws + 786432);    // 786432 u16
    unsigned short* kNb  = (unsigned short*)(ws + 1179648);   // 786432 u16
    unsigned short* scb  = (unsigned short*)(ws + 1572864);   // 3145728 u16
    unsigned short* vtb  = (unsigned short*)(ws + 3145728);   // 12582912 u16
    unsigned short* WvTb = (unsigned short*)(ws + 9437184);   // 16384 u16
    unsigned*       mbp  = (unsigned*)(ws + 9445376);         // 131072 u32

    k1<<<1152, 256, 0, stream>>>(emb, Wqk, bqk, qb, kNb, Wv, WvTb, mask, mbp);
    kF<<<960, 256, 0, stream>>>(qb, kNb, scb, value, WvTb, bvv, vtb);
    kC<<<768, 256, 0, stream>>>(scb, mbp, vtb, out);
}

// Round 7
// 154.417 us; speedup vs baseline: 1.0345x; 1.0345x over previous
//
#include <hip/hip_runtime.h>

#define B_ 16
#define T_ 12
#define N_ 512
#define D_ 128
#define E_ 32

typedef __attribute__((ext_vector_type(8))) unsigned short u16x8;
typedef __attribute__((ext_vector_type(8))) __bf16 bf16x8;
typedef __attribute__((ext_vector_type(4))) float f32x4;

static __device__ __forceinline__ unsigned short f2bf(float f) {
    unsigned u = __float_as_uint(f);
    unsigned r = (u + 0x7fffu + ((u >> 16) & 1u)) >> 16;
    return (unsigned short)r;
}

static __device__ __forceinline__ void gld16(const void* src, void* dst) {
    __builtin_amdgcn_global_load_lds(
        (const __attribute__((address_space(1))) unsigned*)src,
        (__attribute__((address_space(3))) unsigned*)dst, 16, 0, 0);
}

// ---------------------------------------------------------------------------
// k1: ALL input-only stages in one wide launch (XCD-swizzled block ids):
//  [0,192):     kN: qk recomputed from emb (gld16-staged swizzled LDS),
//               softmax over n -> kN bf16.
//  [192,576):   qProj: qk row + softmax over D -> qb bf16 (wave-autonomous).
//  [576,1088):  mask -> packed bitwords
//  [1088,1152): WvT[d][k] = bf16(Wv[k][d])
// ---------------------------------------------------------------------------
__global__ __launch_bounds__(256) void k1(const float* __restrict__ emb,
                                          const float* __restrict__ Wqk,
                                          const float* __restrict__ bqk,
                                          unsigned short* __restrict__ qb,
                                          unsigned short* __restrict__ kN,
                                          const float* __restrict__ Wv,
                                          unsigned short* __restrict__ WvT,
                                          const int* __restrict__ mask,
                                          unsigned* __restrict__ mb) {
    __shared__ __align__(16) char LE[256 * 128];  // 32 KB: 256 emb rows swizzled
    __shared__ float red[2][4][8];
    int hwid = blockIdx.x;
    int bid = (hwid & 7) * 144 + (hwid >> 3);  // XCD swizzle (1152 = 8*144)
    int tid = threadIdx.x;

    if (bid < 192) {  // ---- kN: softmax over n ----
        int t = bid >> 4;
        int d0 = (bid & 15) * 8;
        int dc = tid & 7, ni = tid >> 3;  // ni 0..31
        int wave = tid >> 6, lane = tid & 63;
        int l3 = lane >> 3, l7 = lane & 7;
        float wqv[E_];
#pragma unroll
        for (int e = 0; e < E_; ++e) wqv[e] = Wqk[e * D_ + d0 + dc];
        float bq = bqk[d0 + dc];
        const char* eb = (const char*)(emb + (size_t)t * N_ * E_);

        float vals[16];
#pragma unroll
        for (int pass = 0; pass < 2; ++pass) {
#pragma unroll
            for (int it = 0; it < 8; ++it) {
                int rl = it * 32 + wave * 8 + l3;          // local row 0..255
                int rg = pass * 256 + rl;                  // global row
                gld16(eb + (size_t)rg * 128 + ((l7 * 16) ^ ((rg & 7) << 4)),
                      LE + (it * 32 + wave * 8) * 128 + lane * 16);
            }
            __syncthreads();
#pragma unroll
            for (int jj = 0; jj < 8; ++jj) {
                int n = pass * 256 + ni + 32 * jj;
                int nl = ni + 32 * jj;
                float a = bq;
#pragma unroll
                for (int s = 0; s < 8; ++s) {
                    f32x4 ev = *(const f32x4*)(LE + nl * 128 +
                                               ((s * 16) ^ ((n & 7) << 4)));
                    a = fmaf(ev[0], wqv[s * 4 + 0], a);
                    a = fmaf(ev[1], wqv[s * 4 + 1], a);
                    a = fmaf(ev[2], wqv[s * 4 + 2], a);
                    a = fmaf(ev[3], wqv[s * 4 + 3], a);
                }
                vals[pass * 8 + jj] = a;
            }
            __syncthreads();
        }

        float mx = -1e30f;
#pragma unroll
        for (int j = 0; j < 16; ++j) mx = fmaxf(mx, vals[j]);
#pragma unroll
        for (int s = 8; s < 64; s <<= 1) mx = fmaxf(mx, __shfl_xor(mx, s));
        int wv = tid >> 6;
        if ((tid & 63) < 8) red[0][wv][dc] = mx;
        __syncthreads();
        mx = fmaxf(fmaxf(red[0][0][dc], red[0][1][dc]),
                   fmaxf(red[0][2][dc], red[0][3][dc]));
        float sum = 0.f;
#pragma unroll
        for (int j = 0; j < 16; ++j) {
            vals[j] = __expf(vals[j] - mx);
            sum += vals[j];
        }
#pragma unroll
        for (int s = 8; s < 64; s <<= 1) sum += __shfl_xor(sum, s);
        if ((tid & 63) < 8) red[1][wv][dc] = sum;
        __syncthreads();
        sum = red[1][0][dc] + red[1][1][dc] + red[1][2][dc] + red[1][3][dc];
        float inv = 1.f / sum;
        unsigned short* op = kN + (size_t)t * N_ * D_ + d0 + dc;
#pragma unroll
        for (int j = 0; j < 16; ++j)
            op[(size_t)(ni + 32 * j) * D_] = f2bf(vals[j] * inv);
        return;
    }

    if (bid < 576) {  // ---- qProj + softmax over D ----
        int bid2 = bid - 192;
        int w = tid >> 6, l = tid & 63;
        float wq0[E_], wq1[E_];
#pragma unroll
        for (int e = 0; e < E_; ++e) {
            wq0[e] = Wqk[e * D_ + l];
            wq1[e] = Wqk[e * D_ + l + 64];
        }
        float b0 = bqk[l], b1 = bqk[l + 64];
        for (int rr = 0; rr < 4; ++rr) {
            int tn = bid2 * 16 + w * 4 + rr;  // wave-uniform
            const float* ep = emb + (size_t)tn * E_;
            float a0 = b0, a1 = b1;
#pragma unroll
            for (int e = 0; e < E_; ++e) {
                float ev = ep[e];
                a0 = fmaf(ev, wq0[e], a0);
                a1 = fmaf(ev, wq1[e], a1);
            }
            float mx = fmaxf(a0, a1);
#pragma unroll
            for (int s = 32; s > 0; s >>= 1) mx = fmaxf(mx, __shfl_xor(mx, s));
            float e0 = __expf(a0 - mx), e1 = __expf(a1 - mx);
            float sum = e0 + e1;
#pragma unroll
            for (int s = 32; s > 0; s >>= 1) sum += __shfl_xor(sum, s);
            float inv = 1.f / sum;
            qb[(size_t)tn * D_ + l] = f2bf(e0 * inv);
            qb[(size_t)tn * D_ + l + 64] = f2bf(e1 * inv);
        }
        return;
    }

    if (bid < 1088) {  // ---- mask pack ----
        int o = (bid - 576) * 256 + tid;  // 0..131071
        const int* mp = mask + (size_t)o * 32;
        unsigned bits = 0;
#pragma unroll
        for (int j = 0; j < 32; j += 4) {
            int4 m4 = *(const int4*)&mp[j];
            bits |= (m4.x ? 1u : 0u) << j;
            bits |= (m4.y ? 1u : 0u) << (j + 1);
            bits |= (m4.z ? 1u : 0u) << (j + 2);
            bits |= (m4.w ? 1u : 0u) << (j + 3);
        }
        mb[o] = bits;
        return;
    }

    {  // ---- WvT ----
        int i = (bid - 1088) * 256 + tid;  // 0..16383
        int d = i >> 7, k = i & 127;
        WvT[d * 128 + k] = f2bf(Wv[k * 128 + d]);
    }
}

// ---------------------------------------------------------------------------
// kF: 2-chunk K-split pipeline (anchor, r4/r5 structure), XCD-swizzled ids.
//  [0,192):   A3m: sc = qb @ kN^T
//  [192,960): Bm:  vT[bt][d][m] = WvT @ value^T + bv (value fp32 reg-staged)
// ---------------------------------------------------------------------------
__global__ __launch_bounds__(256, 2) void kF(const unsigned short* __restrict__ qb,
                                             const unsigned short* __restrict__ kN,
                                             unsigned short* __restrict__ sc,
                                             const float* __restrict__ value,
                                             const unsigned short* __restrict__ WvT,
                                             const float* __restrict__ bv,
                                             unsigned short* __restrict__ vT) {
    __shared__ __align__(16) char LA[2][128 * 128];  // 32 KB (A tile, 2 chunks)
    __shared__ __align__(16) char LB[2][128 * 128];  // 32 KB (B tile, 2 chunks)
    int hwid = blockIdx.x;
    int bid = (hwid & 7) * 120 + (hwid >> 3);  // XCD swizzle (960 = 8*120)
    int tid = threadIdx.x;
    int wave = tid >> 6, lane = tid & 63;
    int q = lane >> 4, lr = lane & 15;
    int rbase = (wave & 1) * 64, cbase = (wave >> 1) * 64;
    int l3 = lane >> 3, l7 = lane & 7;

    f32x4 acc[4][4];
#pragma unroll
    for (int i = 0; i < 4; ++i)
#pragma unroll
        for (int j = 0; j < 4; ++j) acc[i][j] = (f32x4){0.f, 0.f, 0.f, 0.f};

#define STAGE_T(gbase, lb, c)                                                   \
    _Pragma("unroll") for (int it_ = 0; it_ < 4; ++it_) {                       \
        int row_ = it_ * 32 + wave * 8 + l3;                                    \
        gld16((gbase) + (size_t)row_ * 256 + (c) * 128 +                        \
                  ((l7 * 16) ^ ((row_ & 7) << 4)),                              \
              (lb) + (it_ * 32 + wave * 8) * 128 + lane * 16);                  \
    }

#define MFMA_CHUNK(c)                                                           \
    _Pragma("unroll") for (int ksl_ = 0; ksl_ < 2; ++ksl_) {                    \
        bf16x8 a_[4], b_[4];                                                    \
        _Pragma("unroll") for (int i_ = 0; i_ < 4; ++i_) {                      \
            int r_ = rbase + 16 * i_ + lr;                                      \
            a_[i_] = *(const bf16x8*)(LA[c] + r_ * 128 +                        \
                                      ((ksl_ * 64 + q * 16) ^ ((r_ & 7) << 4)));\
        }                                                                       \
        _Pragma("unroll") for (int j_ = 0; j_ < 4; ++j_) {                      \
            int r_ = cbase + 16 * j_ + lr;                                      \
            b_[j_] = *(const bf16x8*)(LB[c] + r_ * 128 +                        \
                                      ((ksl_ * 64 + q * 16) ^ ((r_ & 7) << 4)));\
        }                                                                       \
        _Pragma("unroll") for (int i_ = 0; i_ < 4; ++i_)                        \
            _Pragma("unroll") for (int j_ = 0; j_ < 4; ++j_)                    \
                acc[i_][j_] = __builtin_amdgcn_mfma_f32_16x16x32_bf16(          \
                    a_[i_], b_[j_], acc[i_][j_], 0, 0, 0);                      \
    }

    if (bid < 192) {  // ---- A3m ----
        int mt = bid & 3, nt = (bid >> 2) & 3, t = bid >> 4;
        int n0 = nt * 128, m0 = mt * 128;
        const char* qp = (const char*)(qb + (size_t)t * N_ * D_ + (size_t)n0 * D_);
        const char* kp = (const char*)(kN + (size_t)t * N_ * D_ + (size_t)m0 * D_);
        STAGE_T(qp, LA[0], 0)
        STAGE_T(kp, LB[0], 0)
        STAGE_T(qp, LA[1], 1)
        STAGE_T(kp, LB[1], 1)
        asm volatile("s_waitcnt vmcnt(8)" ::: "memory");
        __builtin_amdgcn_sched_barrier(0);
        __builtin_amdgcn_s_barrier();
        __builtin_amdgcn_sched_barrier(0);
        MFMA_CHUNK(0)
        asm volatile("s_waitcnt vmcnt(0)" ::: "memory");
        __builtin_amdgcn_sched_barrier(0);
        __builtin_amdgcn_s_barrier();
        __builtin_amdgcn_sched_barrier(0);
        MFMA_CHUNK(1)

        unsigned short* sp = sc + (size_t)t * N_ * N_;
#pragma unroll
        for (int i = 0; i < 4; ++i)
#pragma unroll
            for (int j = 0; j < 4; ++j) {
                int row0 = n0 + rbase + 16 * i + q * 4;
                int col = m0 + cbase + 16 * j + lr;
#pragma unroll
                for (int e = 0; e < 4; ++e)
                    sp[(size_t)(row0 + e) * N_ + col] = f2bf(acc[i][j][e]);
            }
        return;
    }

    // ---- Bm ----
    {
        int idx = bid - 192;
        int mt = idx & 3, bt = idx >> 2;
        int m0 = mt * 128;
        const float* vp = value + ((size_t)bt * N_ + m0) * D_;
        const char* wp = (const char*)WvT;
        int g = tid >> 4, c16 = tid & 15;

        float4 v0[8], v1[8];
#pragma unroll
        for (int jj = 0; jj < 8; ++jj)
            v0[jj] = *(const float4*)(vp + (size_t)(g * 8 + jj) * D_ + c16 * 4);
        __builtin_amdgcn_sched_barrier(0);
        STAGE_T(wp, LA[0], 0)
        __builtin_amdgcn_sched_barrier(0);
#pragma unroll
        for (int jj = 0; jj < 8; ++jj)
            v1[jj] = *(const float4*)(vp + (size_t)(g * 8 + jj) * D_ + 64 + c16 * 4);
        __builtin_amdgcn_sched_barrier(0);
        STAGE_T(wp, LA[1], 1)
        __builtin_amdgcn_sched_barrier(0);

#pragma unroll
        for (int jj = 0; jj < 8; ++jj) {
            int row = g * 8 + jj;
            ushort4 o;
            o.x = f2bf(v0[jj].x); o.y = f2bf(v0[jj].y);
            o.z = f2bf(v0[jj].z); o.w = f2bf(v0[jj].w);
            *(ushort4*)(LB[0] + row * 128 + ((c16 * 8) ^ ((row & 7) << 4))) = o;
        }
        asm volatile("s_waitcnt vmcnt(12) lgkmcnt(0)" ::: "memory");
        __builtin_amdgcn_sched_barrier(0);
        __builtin_amdgcn_s_barrier();
        __builtin_amdgcn_sched_barrier(0);
        MFMA_CHUNK(0)
#pragma unroll
        for (int jj = 0; jj < 8; ++jj) {
            int row = g * 8 + jj;
            ushort4 o;
            o.x = f2bf(v1[jj].x); o.y = f2bf(v1[jj].y);
            o.z = f2bf(v1[jj].z); o.w = f2bf(v1[jj].w);
            *(ushort4*)(LB[1] + row * 128 + ((c16 * 8) ^ ((row & 7) << 4))) = o;
        }
        asm volatile("s_waitcnt vmcnt(0) lgkmcnt(0)" ::: "memory");
        __builtin_amdgcn_sched_barrier(0);
        __builtin_amdgcn_s_barrier();
        __builtin_amdgcn_sched_barrier(0);
        MFMA_CHUNK(1)

        unsigned short* op = vT + (size_t)bt * N_ * D_;
#pragma unroll
        for (int i = 0; i < 4; ++i) {
            int row0 = rbase + 16 * i + q * 4;
            float4 bq = *(const float4*)&bv[row0];
#pragma unroll
            for (int j = 0; j < 4; ++j) {
                int col = m0 + cbase + 16 * j + lr;
                op[(size_t)(row0 + 0) * N_ + col] = f2bf(acc[i][j][0] + bq.x);
                op[(size_t)(row0 + 1) * N_ + col] = f2bf(acc[i][j][1] + bq.y);
                op[(size_t)(row0 + 2) * N_ + col] = f2bf(acc[i][j][2] + bq.z);
                op[(size_t)(row0 + 3) * N_ + col] = f2bf(acc[i][j][3] + bq.w);
            }
        }
    }
#undef STAGE_T
#undef MFMA_CHUNK
}

// ---------------------------------------------------------------------------
// kC: r5 anchor (3 blocks/CU, 48 KB LDS) with ONE micro-opt: the V(kc+1)
// prefetch is issued BEFORE the merge (pinned), so the merge's implicit
// sreg wait becomes vmcnt(4) instead of vmcnt(0) — V(kc+1) gains the merge
// duration of extra flight. Structure otherwise identical to r5.
// ---------------------------------------------------------------------------
__global__ __launch_bounds__(256, 3) void kC(const unsigned short* __restrict__ sc,
                                             const unsigned* __restrict__ mb,
                                             const unsigned short* __restrict__ vT,
                                             float* __restrict__ out) {
    int hwid = blockIdx.x;
    int w = (hwid & 7) * 96 + (hwid >> 3);  // XCD swizzle (768 = 8*96)
    int n0 = (w & 3) * 128;
    int r = w >> 2;
    int t = r % T_, b = r / T_;
    int tid = threadIdx.x;
    int wave = tid >> 6, lane = tid & 63;
    int q = lane >> 4, lr = lane & 15;
    int rbase = (wave & 1) * 64, cbase = (wave >> 1) * 64;

    __shared__ unsigned short Sb[128 * 64];
    __shared__ unsigned short Vb[2][128 * 64];

    const unsigned short* scp = sc + (size_t)t * N_ * N_ + (size_t)n0 * N_;
    const unsigned short* vtp = vT + ((size_t)(b * T_ + t)) * N_ * D_;  // [d][m]
    const unsigned* mbp = mb + ((size_t)b * N_ + n0) * 16;
    const unsigned short NEG = 0xCE6E;  // bf16(-1e9)

    f32x4 acc[4][4];
#pragma unroll
    for (int i = 0; i < 4; ++i)
#pragma unroll
        for (int j = 0; j < 4; ++j) acc[i][j] = (f32x4){0.f, 0.f, 0.f, 0.f};

    int sr = tid >> 1, sh2 = tid & 1;
    const unsigned short* sg = scp + (size_t)sr * N_ + sh2 * 32;
    const unsigned* mwp = mbp + sr * 16 + sh2;
    int swz_r = (sr & 7) << 4;
    char* Sw[4];
#pragma unroll
    for (int p = 0; p < 4; ++p)
        Sw[p] = (char*)Sb + sr * 128 + ((sh2 * 64 + p * 16) ^ swz_r);

    int l3 = lane >> 3, l7 = lane & 7;
    int vin = (l7 * 16) ^ (l3 << 4);
    const char* vbase = (const char*)vtp;

#pragma unroll
    for (int it = 0; it < 4; ++it) {
        int row = (it * 4 + wave) * 8 + l3;
        const char* src = vbase + (size_t)row * 1024 + vin;
        char* dst = (char*)&Vb[0][0] + ((it * 4 + wave) * 64 + lane) * 16;
        gld16(src, dst);
    }
    u16x8 sreg[4];
    unsigned mw;
#pragma unroll
    for (int p = 0; p < 4; ++p) sreg[p] = *(const u16x8*)(sg + p * 8);
    mw = mwp[0];

    for (int kc = 0; kc < 8; ++kc) {
        int cur = kc & 1;
        // 1. prefetch V(kc+1) FIRST (so the merge's sreg wait keeps it in flight)
        if (kc < 7) {
            int off = (kc + 1) * 128;
#pragma unroll
            for (int it = 0; it < 4; ++it) {
                int row = (it * 4 + wave) * 8 + l3;
                const char* src = vbase + (size_t)row * 1024 + off + vin;
                char* dst = (char*)&Vb[cur ^ 1][0] + ((it * 4 + wave) * 64 + lane) * 16;
                gld16(src, dst);
            }
        }
        __builtin_amdgcn_sched_barrier(0);
        // 2. masked merge of sreg(kc) -> Sb (implicit wait now vmcnt(4))
#pragma unroll
        for (int p = 0; p < 4; ++p) {
            unsigned bits = mw >> (p * 8);
            u16x8 o;
#pragma unroll
            for (int j = 0; j < 8; ++j)
                o[j] = ((bits >> j) & 1u) ? sreg[p][j] : NEG;
            *(u16x8*)Sw[p] = o;
        }
        // 3. load sreg(kc+1) (drains at next iteration's merge)
        if (kc < 7) {
            int eoff = (kc + 1) * 64;
#pragma unroll
            for (int p = 0; p < 4; ++p) sreg[p] = *(const u16x8*)(sg + eoff + p * 8);
            mw = mwp[(kc + 1) * 2];
        }
        // 4. own ds_writes visible, then sync (V(kc+1) stays in flight)
        asm volatile("s_waitcnt lgkmcnt(0)" ::: "memory");
        __builtin_amdgcn_s_barrier();
        __builtin_amdgcn_sched_barrier(0);
        // 5. MFMA from Sb / Vb[cur]
        {
            const char* Sbase = (const char*)Sb;
            const char* Vbase = (const char*)&Vb[cur][0];
            int swz_l = (lr & 7) << 4;
#pragma unroll
            for (int ks = 0; ks < 2; ++ks) {
                bf16x8 a[4], bb[4];
#pragma unroll
                for (int i = 0; i < 4; ++i) {
                    int rr = rbase + 16 * i + lr;
                    a[i] = *(const bf16x8*)(Sbase + rr * 128 + ((ks * 64 + q * 16) ^ swz_l));
                }
#pragma unroll
                for (int j = 0; j < 4; ++j) {
                    int d = cbase + 16 * j + lr;
                    bb[j] = *(const bf16x8*)(Vbase + d * 128 + ((ks * 64 + q * 16) ^ swz_l));
                }
#pragma unroll
                for (int i = 0; i < 4; ++i)
#pragma unroll
                    for (int j = 0; j < 4; ++j)
                        acc[i][j] = __builtin_amdgcn_mfma_f32_16x16x32_bf16(
                            a[i], bb[j], acc[i][j], 0, 0, 0);
            }
        }
        // 6. protect Sb / Vb[cur^1] from next iteration's overwrite
        __builtin_amdgcn_s_barrier();
        __builtin_amdgcn_sched_barrier(0);
    }

    float* ob = out + ((size_t)(b * T_ + t)) * N_ * D_;
#pragma unroll
    for (int i = 0; i < 4; ++i) {
#pragma unroll
        for (int j = 0; j < 4; ++j) {
            int row0 = n0 + rbase + 16 * i + q * 4;
            int col = cbase + 16 * j + lr;
#pragma unroll
            for (int e = 0; e < 4; ++e)
                ob[(size_t)(row0 + e) * D_ + col] = acc[i][j][e];
        }
    }
}

// ---------------------------------------------------------------------------
extern "C" void kernel_launch(void* const* d_in, const int* in_sizes, int n_in,
                              void* d_out, int out_size, void* d_ws, size_t ws_size,
                              hipStream_t stream) {
    const float* value = (const float*)d_in[0];
    const float* emb   = (const float*)d_in[1];
    const int*   mask  = (const int*)d_in[2];
    const float* Wqk   = (const float*)d_in[3];
    const float* bqk   = (const float*)d_in[4];
    const float* Wv    = (const float*)d_in[5];
    const float* bvv   = (const float*)d_in[6];
    float* out = (float*)d_out;

    float* ws = (float*)d_ws;
    unsigned short* qb   = (unsigned short*)(ws + 786432);    // 786432 u16
    unsigned short* kNb  = (unsigned short*)(ws + 1179648);   // 786432 u16
    unsigned short* scb  = (unsigned short*)(ws + 1572864);   // 3145728 u16
    unsigned short* vtb  = (unsigned short*)(ws + 3145728);   // 12582912 u16
    unsigned short* WvTb = (unsigned short*)(ws + 9437184);   // 16384 u16
    unsigned*       mbp  = (unsigned*)(ws + 9445376);         // 131072 u32

    k1<<<1152, 256, 0, stream>>>(emb, Wqk, bqk, qb, kNb, Wv, WvTb, mask, mbp);
    kF<<<960, 256, 0, stream>>>(qb, kNb, scb, value, WvTb, bvv, vtb);
    kC<<<768, 256, 0, stream>>>(scb, mbp, vtb, out);
}